// Round 4
// baseline (666.842 us; speedup 1.0000x reference)
//
#include <hip/hip_runtime.h>
#include <math.h>

#define NTOK 2048        // b*n
#define DIM_ 1024
#define NSEQ 1024
#define HEADS_ 16
#define HD 64
#define MLP_ 4096
#define EPS_ 1e-5f

#define FLAG_BIAS  1
#define FLAG_GELU  2
#define FLAG_QKV   8
#define FLAG_PART  16

typedef __attribute__((ext_vector_type(8))) short bf16x8;
typedef __attribute__((ext_vector_type(4))) float f32x4;
typedef __attribute__((ext_vector_type(16))) float f32x16;

__device__ __forceinline__ unsigned short f2bf(float f) {   // RNE f32->bf16
    unsigned u = __float_as_uint(f);
    u += 0x7fffu + ((u >> 16) & 1u);
    return (unsigned short)(u >> 16);
}
__device__ __forceinline__ float bf2f(unsigned short u) {
    return __uint_as_float(((unsigned)u) << 16);
}
__device__ __forceinline__ void gld16(const unsigned short* g, short* l) {
    __builtin_amdgcn_global_load_lds(
        (const __attribute__((address_space(1))) void*)g,
        (__attribute__((address_space(3))) void*)l, 16, 0, 0);
}
// tanh-form GELU via sigmoid: x*sigma(1.59577*(x+0.044715x^3)); |err|<~3e-4,
// below hdn's bf16 rounding. Replaces 64 erff/thread in the mlp1 epilogue.
__device__ __forceinline__ float gelu_fast(float v) {
    float u = 1.5957691f * (v + 0.044715f * v * v * v);
    return v / (1.0f + __expf(-u));
}

// ---------------- weight convert: W[K][N] f32 -> Wt[N][K] bf16 ----------------
__global__ __launch_bounds__(256) void wconv_kernel(const float* __restrict__ W,
                                                    unsigned short* __restrict__ Wt,
                                                    int K, int N,
                                                    float qscale, int qcols) {
    __shared__ float s[32][33];
    int n0 = blockIdx.x * 32, k0 = blockIdx.y * 32;
    int tx = threadIdx.x, ty = threadIdx.y;   // (32,8)
    #pragma unroll
    for (int r = 0; r < 4; r++) {
        int k = ty + r * 8;
        s[k][tx] = W[(size_t)(k0 + k) * N + n0 + tx];
    }
    __syncthreads();
    #pragma unroll
    for (int r = 0; r < 4; r++) {
        int n = ty + r * 8;
        float v = s[tx][n];
        if (n0 + n < qcols) v *= qscale;
        Wt[(size_t)(n0 + n) * K + k0 + tx] = f2bf(v);
    }
}

// ---------------- LayerNorm: fp32 in -> bf16 out (layer-0 ln1 only) ----------------
__global__ __launch_bounds__(256) void ln_kernel(const float* __restrict__ src,
                                                 unsigned short* __restrict__ dst,
                                                 const float* __restrict__ g,
                                                 const float* __restrict__ b) {
    int row = blockIdx.x;
    int t = threadIdx.x;
    const float4* x4 = (const float4*)(src + (size_t)row * DIM_);
    float4 f = x4[t];
    float s  = f.x + f.y + f.z + f.w;
    float sq = f.x*f.x + f.y*f.y + f.z*f.z + f.w*f.w;
    __shared__ float ssum[256], ssq[256];
    ssum[t] = s; ssq[t] = sq;
    __syncthreads();
    for (int o = 128; o > 0; o >>= 1) {
        if (t < o) { ssum[t] += ssum[t+o]; ssq[t] += ssq[t+o]; }
        __syncthreads();
    }
    float mu  = ssum[0] * (1.0f / DIM_);
    float var = ssq[0] * (1.0f / DIM_) - mu * mu;
    float r = rsqrtf(var + EPS_);
    const float4* g4 = (const float4*)g;
    const float4* b4 = (const float4*)b;
    float4 gg = g4[t], bb = b4[t];
    ushort4 o4;
    o4.x = f2bf((f.x - mu) * r * gg.x + bb.x);
    o4.y = f2bf((f.y - mu) * r * gg.y + bb.y);
    o4.z = f2bf((f.z - mu) * r * gg.z + bb.z);
    o4.w = f2bf((f.w - mu) * r * gg.w + bb.w);
    ((ushort4*)(dst + (size_t)row * DIM_))[t] = o4;
}

// ---------------- 128x128 MFMA GEMM, 2 waves, dbuf + counted vmcnt ----------------
// Round-4 structure:
//  - 2 waves/block (128 thr), wave-tile 64x128 = 2x4 frags of 32x32x16 MFMA.
//    FLOP/LDS-byte 32 -> 42.7 (8 MFMA per 6 ds_read_b128 per k-slice vs 4:4).
//    Block tile stays 128x128 -> all grids stay 384-512 blocks (round-1 lesson:
//    the pipeline's prerequisite is grid fill; 256^2 tiles starved CUs).
//  - T3/T4: LDS double-buffered (64KB), depth-2 gld16 prefetch, counted
//    `s_waitcnt vmcnt(16)` at iter top -- tile t+1's 16 loads stay in flight
//    across barriers; never drain to 0 mid-loop (the m97-structure stall).
//    Raw s_barrier + asm memory fences (compiler must not hoist LDS reads
//    across, nor sink the re-stage above the post-compute barrier).
//  - bank-deconflict swizzle unchanged: chunk c of row r stored at c^(r&7) via
//    global-side fetch swizzle; read chunk (ks*2+hi)^(lane&7); row&7==lane&7 on
//    all read paths.
//  - fragment maps (HW-verified m74/m101): A/B row|col = lane&31, k-chunk =
//    (lane>>5)*8; C/D col = lane&31, row = (reg&3)+8*(reg>>2)+4*(lane>>5).
__global__ __launch_bounds__(128, 2) void gemm128_kernel(const unsigned short* __restrict__ A,
                                                         const unsigned short* __restrict__ Bt,
                                                         unsigned short* __restrict__ Cb,
                                                         unsigned short* __restrict__ Vt,
                                                         unsigned short* __restrict__ Ppart,
                                                         const float* __restrict__ bias,
                                                         int M, int N, int K, int KC,
                                                         int ldcb, int nx, int gz, int flags) {
    __shared__ short As[2][128 * 64];
    __shared__ short Bs[2][128 * 64];
    const int BUFS = 128 * 64;   // shorts per buffer

    int id = blockIdx.x;
    int xcd = id & 7, s = id >> 3;
    int x = s % nx, pl = s / nx;
    int pair = pl * 8 + xcd;
    int z = pair % gz, y = pair / gz;
    int col0 = x * 128, row0 = y * 128;
    int k_beg = z * KC;
    int nt = KC >> 6;            // K-steps (>=4 in all our calls)

    int t = threadIdx.x;         // 0..127
    int lane = t & 63, w = t >> 6;          // 2 waves: w = row-half
    int n_l = lane & 31, hi = lane >> 5;
    int x7 = lane & 7;

    f32x16 acc[2][4];
    #pragma unroll
    for (int mi = 0; mi < 2; mi++)
        #pragma unroll
        for (int ni = 0; ni < 4; ni++)
            #pragma unroll
            for (int r = 0; r < 16; r++) acc[mi][ni][r] = 0.f;

    // staging: thread t covers rows r0+16i (i=0..7), r0=t>>3 in 0..15; stored
    // chunk p=t&7 holds logical chunk p^(r0&7) (16i preserves row&7).
    // LDS short index = t*8 + i*1024.
    int r0 = t >> 3;
    int lchunk = ((t & 7) ^ (r0 & 7)) * 8;
    const unsigned short* Ag = A  + (size_t)(row0 + r0) * K + k_beg + lchunk;
    const unsigned short* Bg = Bt + (size_t)(col0 + r0) * K + k_beg + lchunk;
    short* Al = &As[0][t * 8];
    short* Bl = &Bs[0][t * 8];

    auto stage = [&](int buf_, int tt_) {
        #pragma unroll
        for (int i = 0; i < 8; i++) {
            gld16(Ag + tt_ * 64 + (size_t)i * 16 * K, Al + buf_ * BUFS + i * 1024);
            gld16(Bg + tt_ * 64 + (size_t)i * 16 * K, Bl + buf_ * BUFS + i * 1024);
        }
    };
    stage(0, 0);
    if (nt > 1) stage(1, 1);

    for (int tt = 0; tt < nt; tt++) {
        int cur = tt & 1;
        // counted wait: tile tt+1's 16 loads may stay in flight; all older
        // (tile tt, both waves' halves after the barrier) have landed.
        if (tt + 1 < nt) asm volatile("s_waitcnt vmcnt(16)" ::: "memory");
        else             asm volatile("s_waitcnt vmcnt(0)" ::: "memory");
        __builtin_amdgcn_s_barrier();
        asm volatile("" ::: "memory");

        const short* Ab = &As[cur][0];
        const short* Bb = &Bs[cur][0];
        #pragma unroll
        for (int ks = 0; ks < 4; ks++) {
            int cb = ((ks * 2 + hi) ^ x7) * 8;
            bf16x8 af[2], bfr[4];
            #pragma unroll
            for (int mi = 0; mi < 2; mi++)
                af[mi]  = *(const bf16x8*)&Ab[(w * 64 + mi * 32 + n_l) * 64 + cb];
            #pragma unroll
            for (int ni = 0; ni < 4; ni++)
                bfr[ni] = *(const bf16x8*)&Bb[(ni * 32 + n_l) * 64 + cb];
            #pragma unroll
            for (int mi = 0; mi < 2; mi++)
                #pragma unroll
                for (int ni = 0; ni < 4; ni++)
                    acc[mi][ni] = __builtin_amdgcn_mfma_f32_32x32x16_bf16(af[mi], bfr[ni],
                                                                          acc[mi][ni], 0, 0, 0);
        }

        asm volatile("" ::: "memory");
        __builtin_amdgcn_s_barrier();
        asm volatile("" ::: "memory");
        // both waves are past their reads of buf[cur]; re-stage it for tile tt+2.
        if (tt + 2 < nt) stage(cur, tt + 2);
    }

    if (flags & FLAG_PART) {   // bf16 split-K partial
        unsigned short* P = Ppart + (size_t)z * M * N;
        #pragma unroll
        for (int mi = 0; mi < 2; mi++)
            #pragma unroll
            for (int ni = 0; ni < 4; ni++) {
                int col = col0 + ni * 32 + n_l;
                #pragma unroll
                for (int reg = 0; reg < 16; reg++) {
                    int row = row0 + w * 64 + mi * 32 + (reg & 3) + 8 * (reg >> 2) + 4 * hi;
                    P[(size_t)row * N + col] = f2bf(acc[mi][ni][reg]);
                }
            }
        return;
    }

    if ((flags & FLAG_QKV) && col0 >= 2048) {   // V region -> transposed Vt[b,h,d,n]
        #pragma unroll
        for (int mi = 0; mi < 2; mi++)
            #pragma unroll
            for (int g = 0; g < 4; g++) {
                int tok0 = row0 + w * 64 + mi * 32 + g * 8 + 4 * hi;
                int bb = tok0 >> 10, nn = tok0 & 1023;
                #pragma unroll
                for (int ni = 0; ni < 4; ni++) {
                    int cg = col0 - 2048 + ni * 32 + n_l;
                    int h = cg >> 6, d = cg & 63;
                    ushort4 o4;
                    o4.x = f2bf(acc[mi][ni][g * 4 + 0]);
                    o4.y = f2bf(acc[mi][ni][g * 4 + 1]);
                    o4.z = f2bf(acc[mi][ni][g * 4 + 2]);
                    o4.w = f2bf(acc[mi][ni][g * 4 + 3]);
                    *(ushort4*)(Vt + ((size_t)(bb * 16 + h) * 64 + d) * 1024 + nn) = o4;
                }
            }
        return;
    }

    #pragma unroll
    for (int mi = 0; mi < 2; mi++)
        #pragma unroll
        for (int ni = 0; ni < 4; ni++) {
            int col = col0 + ni * 32 + n_l;
            float bv = (flags & FLAG_BIAS) ? bias[col] : 0.0f;
            #pragma unroll
            for (int reg = 0; reg < 16; reg++) {
                int row = row0 + w * 64 + mi * 32 + (reg & 3) + 8 * (reg >> 2) + 4 * hi;
                float v = acc[mi][ni][reg] + bv;
                if (flags & FLAG_GELU) v = gelu_fast(v);
                Cb[(size_t)row * ldcb + col] = f2bf(v);
            }
        }
}

// ---------------- fused split-K reduce (bf16 partials) + residual + optional LN ----------------
__global__ __launch_bounds__(256) void reduce_ln_kernel(const unsigned short* __restrict__ P,
                                                        int nsplit,
                                                        const float* __restrict__ bias,
                                                        const float* __restrict__ resid,
                                                        float* __restrict__ xc_out,
                                                        unsigned short* __restrict__ xn_out,
                                                        const float* __restrict__ g,
                                                        const float* __restrict__ b) {
    const int MN = NTOK * DIM_;
    int row = blockIdx.x;
    int t = threadIdx.x;
    size_t i = (size_t)row * DIM_ + t * 4;
    float4 y  = *(const float4*)(resid + i);
    float4 bi = *(const float4*)(bias + t * 4);
    y.x += bi.x; y.y += bi.y; y.z += bi.z; y.w += bi.w;
    for (int z = 0; z < nsplit; z++) {
        ushort4 p = *(const ushort4*)(P + (size_t)z * MN + i);
        y.x += bf2f(p.x); y.y += bf2f(p.y); y.z += bf2f(p.z); y.w += bf2f(p.w);
    }
    *(float4*)(xc_out + i) = y;
    if (!xn_out) return;

    float s  = y.x + y.y + y.z + y.w;
    float sq = y.x*y.x + y.y*y.y + y.z*y.z + y.w*y.w;
    __shared__ float ssum[256], ssq[256];
    ssum[t] = s; ssq[t] = sq;
    __syncthreads();
    for (int o = 128; o > 0; o >>= 1) {
        if (t < o) { ssum[t] += ssum[t+o]; ssq[t] += ssq[t+o]; }
        __syncthreads();
    }
    float mu  = ssum[0] * (1.0f / DIM_);
    float var = ssq[0] * (1.0f / DIM_) - mu * mu;
    float r = rsqrtf(var + EPS_);
    float4 gg = *(const float4*)(g + t * 4);
    float4 bb = *(const float4*)(b + t * 4);
    ushort4 o4;
    o4.x = f2bf((y.x - mu) * r * gg.x + bb.x);
    o4.y = f2bf((y.y - mu) * r * gg.y + bb.y);
    o4.z = f2bf((y.z - mu) * r * gg.z + bb.z);
    o4.w = f2bf((y.w - mu) * r * gg.w + bb.w);
    ((ushort4*)(xn_out + (size_t)row * DIM_))[t] = o4;
}

// ---------------- MFMA flash attention v3 (round-2 winner, unchanged) ----------------
//  - T14 async-STAGE: K/V double-buffered in LDS; tile t+1's global loads are
//    issued into registers right after the barrier and written at the top of
//    t+1, so HBM/L2 latency hides under QK+softmax+PV compute.
//  - single barrier per j-tile; Ps is wave-private.
//  - T1 XCD grouping: qt on HIGH index bits -> 8 q-blocks sharing one (b,h)'s
//    K/V are congruent mod 8 -> same XCD L2.
__global__ __launch_bounds__(512) void fattn_kernel(const unsigned short* __restrict__ qk,
                                                    const unsigned short* __restrict__ VtG,
                                                    unsigned short* __restrict__ out) {
    int idx = blockIdx.x;
    int qt = idx >> 5;           // 0..7
    int h  = idx & 15;
    int b  = (idx >> 4) & 1;
    int t  = threadIdx.x;
    int lane = t & 63, w = t >> 6;
    int m = lane & 15, quad = lane >> 4;

    __shared__ unsigned short Ks[2][64 * 64];    // [j][d], swizzled, double-buffered
    __shared__ unsigned short Vs[2][64 * 64];    // [d][j], swizzled, double-buffered
    __shared__ unsigned short Ps[8][16 * 72];    // per-wave P [i][j], padded

    const size_t base = (size_t)b * NSEQ * 2048;
    const int i0 = qt * 128 + w * 16;

    bf16x8 aq0, aq1;
    {
        const unsigned short* qrow = qk + base + (size_t)(i0 + m) * 2048 + h * HD;
        aq0 = *(const bf16x8*)(qrow + quad * 8);
        aq1 = *(const bf16x8*)(qrow + 32 + quad * 8);
    }

    f32x4 Oacc[4];
    #pragma unroll
    for (int dt = 0; dt < 4; dt++) Oacc[dt] = (f32x4){0.f, 0.f, 0.f, 0.f};
    float lsum[4] = {0.f, 0.f, 0.f, 0.f};

    int srow = t >> 3;                 // 0..63
    int schunk = t & 7;
    int swc = schunk ^ (srow & 7);
    const unsigned short* Kg = qk + base + 1024 + h * HD + (size_t)srow * 2048 + schunk * 8;
    const unsigned short* Vg = VtG + ((size_t)(b * 16 + h) * 64 + srow) * 1024 + schunk * 8;
    const int sloff = srow * 64 + swc * 8;

    // prefetch tile 0 into registers
    bf16x8 kreg = *(const bf16x8*)(Kg);
    bf16x8 vreg = *(const bf16x8*)(Vg);

    for (int jt = 0; jt < NSEQ / 64; jt++) {
        int cur = jt & 1;
        *(bf16x8*)&Ks[cur][sloff] = kreg;
        *(bf16x8*)&Vs[cur][sloff] = vreg;
        __syncthreads();
        if (jt + 1 < NSEQ / 64) {       // issue next tile now; lands during compute
            kreg = *(const bf16x8*)(Kg + (size_t)(jt + 1) * 64 * 2048);
            vreg = *(const bf16x8*)(Vg + (jt + 1) * 64);
        }

        f32x4 s[4];
        #pragma unroll
        for (int nt = 0; nt < 4; nt++) {
            int jr = nt * 16 + m;
            const unsigned short* kr = &Ks[cur][jr * 64];
            int x7 = jr & 7;
            bf16x8 b0 = *(const bf16x8*)(kr + (quad ^ x7) * 8);
            bf16x8 b1 = *(const bf16x8*)(kr + ((quad + 4) ^ x7) * 8);
            f32x4 a = (f32x4){0.f, 0.f, 0.f, 0.f};
            a = __builtin_amdgcn_mfma_f32_16x16x32_bf16(aq0, b0, a, 0, 0, 0);
            a = __builtin_amdgcn_mfma_f32_16x16x32_bf16(aq1, b1, a, 0, 0, 0);
            s[nt] = a;
        }

        #pragma unroll
        for (int r = 0; r < 4; r++) {
            float p0 = __expf(s[0][r]);
            float p1 = __expf(s[1][r]);
            float p2 = __expf(s[2][r]);
            float p3 = __expf(s[3][r]);
            lsum[r] += p0 + p1 + p2 + p3;
            unsigned short* pr = &Ps[w][(quad * 4 + r) * 72 + m];
            pr[0]  = f2bf(p0);
            pr[16] = f2bf(p1);
            pr[32] = f2bf(p2);
            pr[48] = f2bf(p3);
        }

        const unsigned short* pa = &Ps[w][m * 72 + quad * 8];
        bf16x8 ap0 = *(const bf16x8*)pa;
        bf16x8 ap1 = *(const bf16x8*)(pa + 32);
        #pragma unroll
        for (int dt = 0; dt < 4; dt++) {
            int dr = dt * 16 + m;
            const unsigned short* vr = &Vs[cur][dr * 64];
            int x7 = dr & 7;
            bf16x8 b0 = *(const bf16x8*)(vr + (quad ^ x7) * 8);
            bf16x8 b1 = *(const bf16x8*)(vr + ((quad + 4) ^ x7) * 8);
            Oacc[dt] = __builtin_amdgcn_mfma_f32_16x16x32_bf16(ap0, b0, Oacc[dt], 0, 0, 0);
            Oacc[dt] = __builtin_amdgcn_mfma_f32_16x16x32_bf16(ap1, b1, Oacc[dt], 0, 0, 0);
        }
        // no trailing barrier: next iter writes the other LDS buffer
    }

    #pragma unroll
    for (int r = 0; r < 4; r++) {
        float rs = lsum[r];
        rs += __shfl_xor(rs, 1);
        rs += __shfl_xor(rs, 2);
        rs += __shfl_xor(rs, 4);
        rs += __shfl_xor(rs, 8);
        lsum[r] = rs;
    }

    #pragma unroll
    for (int r = 0; r < 4; r++) {
        float inv = 1.0f / lsum[r];
        int row = i0 + quad * 4 + r;
        unsigned short* orow = out + ((size_t)(b * NSEQ + row)) * DIM_ + h * HD + m;
        orow[0]  = f2bf(Oacc[0][r] * inv);
        orow[16] = f2bf(Oacc[1][r] * inv);
        orow[32] = f2bf(Oacc[2][r] * inv);
        orow[48] = f2bf(Oacc[3][r] * inv);
    }
}

extern "C" void kernel_launch(void* const* d_in, const int* in_sizes, int n_in,
                              void* d_out, int out_size, void* d_ws, size_t ws_size,
                              hipStream_t stream) {
    const float* x    = (const float*)d_in[0];
    const float* ln1g = (const float*)d_in[1];
    const float* ln1b = (const float*)d_in[2];
    const float* wqkv = (const float*)d_in[3];
    const float* wo   = (const float*)d_in[4];
    const float* bo   = (const float*)d_in[5];
    const float* ln2g = (const float*)d_in[6];
    const float* ln2b = (const float*)d_in[7];
    const float* w1   = (const float*)d_in[8];
    const float* b1   = (const float*)d_in[9];
    const float* w2   = (const float*)d_in[10];
    const float* b2   = (const float*)d_in[11];
    float* out = (float*)d_out;

    // layout (MB): xcur 0-8 | aout 8-12 | xn 12-16 | qk 16-24 | VtG 24-28 |
    //              hdn 28-44 | wtqkv 44-50 | wto 50-52 | wt1 52-60 | wt2 60-68
    // overlays (bf16 split-K partials, 4 x 4MB = 16MB):
    //   o-partials    @12-28 (xn+qk+VtG dead during o-gemm)
    //   mlp2-partials @ 8-24 (aout+xn+qk dead during mlp2-gemm)
    char* ws = (char*)d_ws;
    float*          xcur = (float*)(ws);
    unsigned short* aout = (unsigned short*)(ws + (8u<<20));
    unsigned short* xn   = (unsigned short*)(ws + (12u<<20));
    unsigned short* qk   = (unsigned short*)(ws + (16u<<20));
    unsigned short* VtG  = (unsigned short*)(ws + (24u<<20));
    unsigned short* hdn  = (unsigned short*)(ws + (28u<<20));
    unsigned short* wtqkv= (unsigned short*)(ws + (44u<<20));
    unsigned short* wto  = (unsigned short*)(ws + (50u<<20));
    unsigned short* wt1  = (unsigned short*)(ws + (52u<<20));
    unsigned short* wt2  = (unsigned short*)(ws + (60u<<20));
    unsigned short* opart  = (unsigned short*)(ws + (12u<<20));
    unsigned short* m2part = (unsigned short*)(ws + (8u<<20));

    wconv_kernel<<<dim3(3*DIM_/32, DIM_/32), dim3(32,8), 0, stream>>>(wqkv, wtqkv, DIM_, 3*DIM_,
                                                                      0.03125f, DIM_);
    wconv_kernel<<<dim3(DIM_/32,   DIM_/32), dim3(32,8), 0, stream>>>(wo,   wto, DIM_, DIM_, 1.f, 0);
    wconv_kernel<<<dim3(MLP_/32,   DIM_/32), dim3(32,8), 0, stream>>>(w1,   wt1, DIM_, MLP_, 1.f, 0);
    wconv_kernel<<<dim3(DIM_/32,   MLP_/32), dim3(32,8), 0, stream>>>(w2,   wt2, MLP_, DIM_, 1.f, 0);

    for (int layer = 0; layer < 4; layer++) {
        if (layer == 0)
            ln_kernel<<<NTOK, 256, 0, stream>>>(x, xn, ln1g, ln1b);
        // qkv: 384 blocks (nx=24, gy=16, gz=1); Q,K -> qk (stride 2048); V -> VtG
        gemm128_kernel<<<384, 128, 0, stream>>>(
            xn, wtqkv, qk, VtG, nullptr, nullptr,
            NTOK, 3*DIM_, DIM_, DIM_, 2048, 24, 1, FLAG_QKV);
        fattn_kernel<<<256, 512, 0, stream>>>(qk, VtG, aout);
        // o-proj: SK=4 (nx=8, gy=16, gz=4), KC=256 -> bf16 partials
        gemm128_kernel<<<512, 128, 0, stream>>>(
            aout, wto, nullptr, nullptr, opart, nullptr,
            NTOK, DIM_, DIM_, DIM_/4, 0, 8, 4, FLAG_PART);
        reduce_ln_kernel<<<NTOK, 256, 0, stream>>>(
            opart, 4, bo, (layer == 0 ? x : xcur), xcur, xn, ln2g, ln2b);
        // mlp1: 512 blocks (nx=32, gy=16, gz=1); bias+gelu, bf16 out
        gemm128_kernel<<<512, 128, 0, stream>>>(
            xn, wt1, hdn, nullptr, nullptr, b1,
            NTOK, MLP_, DIM_, DIM_, MLP_, 32, 1, FLAG_BIAS | FLAG_GELU);
        // mlp2: SK=4 (nx=8, gy=16, gz=4), KC=1024 -> bf16 partials
        gemm128_kernel<<<512, 128, 0, stream>>>(
            hdn, wt2, nullptr, nullptr, m2part, nullptr,
            NTOK, DIM_, MLP_, MLP_/4, 0, 8, 4, FLAG_PART);
        if (layer < 3)
            reduce_ln_kernel<<<NTOK, 256, 0, stream>>>(
                m2part, 4, b2, xcur, xcur, xn, ln1g, ln1b);
        else
            reduce_ln_kernel<<<NTOK, 256, 0, stream>>>(
                m2part, 4, b2, xcur, out, nullptr, nullptr, nullptr);
    }
}

// Round 5
// 588.863 us; speedup vs baseline: 1.1324x; 1.1324x over previous
//
#include <hip/hip_runtime.h>
#include <math.h>

#define NTOK 2048        // b*n
#define DIM_ 1024
#define NSEQ 1024
#define HEADS_ 16
#define HD 64
#define MLP_ 4096
#define EPS_ 1e-5f

#define FLAG_BIAS  1
#define FLAG_GELU  2
#define FLAG_QKV   8
#define FLAG_PART  16

typedef __attribute__((ext_vector_type(8))) short bf16x8;
typedef __attribute__((ext_vector_type(4))) float f32x4;
typedef __attribute__((ext_vector_type(16))) float f32x16;

__device__ __forceinline__ unsigned short f2bf(float f) {   // RNE f32->bf16
    unsigned u = __float_as_uint(f);
    u += 0x7fffu + ((u >> 16) & 1u);
    return (unsigned short)(u >> 16);
}
__device__ __forceinline__ float bf2f(unsigned short u) {
    return __uint_as_float(((unsigned)u) << 16);
}
__device__ __forceinline__ void gld16(const unsigned short* g, short* l) {
    __builtin_amdgcn_global_load_lds(
        (const __attribute__((address_space(1))) void*)g,
        (__attribute__((address_space(3))) void*)l, 16, 0, 0);
}
// tanh-form GELU via sigmoid: x*sigma(1.59577*(x+0.044715x^3)); |err|<~3e-4,
// below hdn's bf16 rounding. Replaces 64 erff/thread in the mlp1 epilogue.
__device__ __forceinline__ float gelu_fast(float v) {
    float u = 1.5957691f * (v + 0.044715f * v * v * v);
    return v / (1.0f + __expf(-u));
}

// ---------------- weight convert: W[K][N] f32 -> Wt[N][K] bf16 ----------------
__global__ __launch_bounds__(256) void wconv_kernel(const float* __restrict__ W,
                                                    unsigned short* __restrict__ Wt,
                                                    int K, int N,
                                                    float qscale, int qcols) {
    __shared__ float s[32][33];
    int n0 = blockIdx.x * 32, k0 = blockIdx.y * 32;
    int tx = threadIdx.x, ty = threadIdx.y;   // (32,8)
    #pragma unroll
    for (int r = 0; r < 4; r++) {
        int k = ty + r * 8;
        s[k][tx] = W[(size_t)(k0 + k) * N + n0 + tx];
    }
    __syncthreads();
    #pragma unroll
    for (int r = 0; r < 4; r++) {
        int n = ty + r * 8;
        float v = s[tx][n];
        if (n0 + n < qcols) v *= qscale;
        Wt[(size_t)(n0 + n) * K + k0 + tx] = f2bf(v);
    }
}

// ---------------- LayerNorm: fp32 in -> bf16 out (layer-0 ln1 only) ----------------
__global__ __launch_bounds__(256) void ln_kernel(const float* __restrict__ src,
                                                 unsigned short* __restrict__ dst,
                                                 const float* __restrict__ g,
                                                 const float* __restrict__ b) {
    int row = blockIdx.x;
    int t = threadIdx.x;
    const float4* x4 = (const float4*)(src + (size_t)row * DIM_);
    float4 f = x4[t];
    float s  = f.x + f.y + f.z + f.w;
    float sq = f.x*f.x + f.y*f.y + f.z*f.z + f.w*f.w;
    __shared__ float ssum[256], ssq[256];
    ssum[t] = s; ssq[t] = sq;
    __syncthreads();
    for (int o = 128; o > 0; o >>= 1) {
        if (t < o) { ssum[t] += ssum[t+o]; ssq[t] += ssq[t+o]; }
        __syncthreads();
    }
    float mu  = ssum[0] * (1.0f / DIM_);
    float var = ssq[0] * (1.0f / DIM_) - mu * mu;
    float r = rsqrtf(var + EPS_);
    const float4* g4 = (const float4*)g;
    const float4* b4 = (const float4*)b;
    float4 gg = g4[t], bb = b4[t];
    ushort4 o4;
    o4.x = f2bf((f.x - mu) * r * gg.x + bb.x);
    o4.y = f2bf((f.y - mu) * r * gg.y + bb.y);
    o4.z = f2bf((f.z - mu) * r * gg.z + bb.z);
    o4.w = f2bf((f.w - mu) * r * gg.w + bb.w);
    ((ushort4*)(dst + (size_t)row * DIM_))[t] = o4;
}

// ---------------- 128x128 MFMA GEMM, BK=64, XCD swizzle + bank-deconflict ----------------
// Round-3 proven structure (613us): 256 thr / 4 waves, 32KB LDS, 3-4 blocks/CU.
// 32x32x16 MFMA inner math (m119: +21% pipe rate over 16x16x32).
// Round-4 lesson (667us regression): 128-thr 2-wave + 64KB dbuf left 1 wave/SIMD
// -- no latency hiding. This structure's occupancy (>=3 waves/SIMD via 3+
// blocks/CU) is the latency-hider; keep it.
// Round-5 change: K-loop trip count NT is a template constant (KC is always
// 256 or 1024) -> full unroll, strength-reduced addressing, earlier gld16 issue.
// Fragment maps (HW-verified m74/m101): A/B row|col = lane&31, k-chunk =
// (lane>>5)*8; C/D col = lane&31, row = (reg&3)+8*(reg>>2)+4*(lane>>5).
// LDS swizzle: chunk c of row r stored at c^(r&7) via global-side fetch
// swizzle; read chunk (ks*2+hi)^(lane&7) -> 2 lanes/bank-group = free (m136).
template<int NT>
__global__ __launch_bounds__(256) void gemm128_kernel(const unsigned short* __restrict__ A,
                                                      const unsigned short* __restrict__ Bt,
                                                      unsigned short* __restrict__ Cb,
                                                      unsigned short* __restrict__ Vt,
                                                      unsigned short* __restrict__ Ppart,
                                                      const float* __restrict__ bias,
                                                      int M, int N, int K,
                                                      int ldcb, int nx, int gz, int flags) {
    __shared__ short As[128 * 64];
    __shared__ short Bs[128 * 64];
    int id = blockIdx.x;
    int xcd = id & 7, s = id >> 3;
    int x = s % nx, pl = s / nx;
    int pair = pl * 8 + xcd;
    int z = pair % gz, y = pair / gz;
    int col0 = x * 128, row0 = y * 128;
    int k_beg = z * (NT * 64);

    int t = threadIdx.x;
    int lane = t & 63, w = t >> 6;
    int wm = w & 1, wn = w >> 1;

    f32x16 acc[2][2];
    #pragma unroll
    for (int mi = 0; mi < 2; mi++)
        #pragma unroll
        for (int ni = 0; ni < 2; ni++)
            #pragma unroll
            for (int r = 0; r < 16; r++) acc[mi][ni][r] = 0.f;

    // staging: thread t covers row r0=(t>>3)+i*32, stored chunk p=t&7 holds
    // logical chunk p^(r0&7); LDS short index = t*8 + i*2048 (= row*64 + p*8).
    int r0 = t >> 3;
    int lchunk = ((t & 7) ^ (r0 & 7)) * 8;
    const unsigned short* Ag = A  + (size_t)(row0 + r0) * K + k_beg + lchunk;
    const unsigned short* Bg = Bt + (size_t)(col0 + r0) * K + k_beg + lchunk;
    short* Al = As + t * 8;
    short* Bl = Bs + t * 8;

    int n_l = lane & 31, hi = lane >> 5;
    int x7 = lane & 7;

    #pragma unroll
    for (int tt = 0; tt < NT; tt++) {
        #pragma unroll
        for (int i = 0; i < 4; i++) {
            gld16(Ag + tt * 64 + (size_t)i * 32 * K, Al + i * 2048);
            gld16(Bg + tt * 64 + (size_t)i * 32 * K, Bl + i * 2048);
        }
        __syncthreads();

        #pragma unroll
        for (int ks = 0; ks < 4; ks++) {
            int cb = ((ks * 2 + hi) ^ x7) * 8;
            bf16x8 af[2], bfr[2];
            #pragma unroll
            for (int mi = 0; mi < 2; mi++)
                af[mi]  = *(const bf16x8*)&As[(wm * 64 + mi * 32 + n_l) * 64 + cb];
            #pragma unroll
            for (int ni = 0; ni < 2; ni++)
                bfr[ni] = *(const bf16x8*)&Bs[(wn * 64 + ni * 32 + n_l) * 64 + cb];
            #pragma unroll
            for (int mi = 0; mi < 2; mi++)
                #pragma unroll
                for (int ni = 0; ni < 2; ni++)
                    acc[mi][ni] = __builtin_amdgcn_mfma_f32_32x32x16_bf16(af[mi], bfr[ni],
                                                                          acc[mi][ni], 0, 0, 0);
        }
        __syncthreads();
    }

    if (flags & FLAG_PART) {   // bf16 split-K partial
        unsigned short* P = Ppart + (size_t)z * M * N;
        #pragma unroll
        for (int mi = 0; mi < 2; mi++)
            #pragma unroll
            for (int ni = 0; ni < 2; ni++) {
                int col = col0 + wn * 64 + ni * 32 + n_l;
                #pragma unroll
                for (int reg = 0; reg < 16; reg++) {
                    int row = row0 + wm * 64 + mi * 32 + (reg & 3) + 8 * (reg >> 2) + 4 * hi;
                    P[(size_t)row * N + col] = f2bf(acc[mi][ni][reg]);
                }
            }
        return;
    }

    int colw = col0 + wn * 64;
    if ((flags & FLAG_QKV) && colw >= 2048) {   // V region -> transposed Vt[b,h,d,n]
        int h = (colw - 2048) >> 6;
        #pragma unroll
        for (int mi = 0; mi < 2; mi++)
            #pragma unroll
            for (int g = 0; g < 4; g++) {
                int tok0 = row0 + wm * 64 + mi * 32 + g * 8 + 4 * hi;
                int bb = tok0 >> 10, nn = tok0 & 1023;
                #pragma unroll
                for (int ni = 0; ni < 2; ni++) {
                    int d = ni * 32 + n_l;
                    ushort4 o4;
                    o4.x = f2bf(acc[mi][ni][g * 4 + 0]);
                    o4.y = f2bf(acc[mi][ni][g * 4 + 1]);
                    o4.z = f2bf(acc[mi][ni][g * 4 + 2]);
                    o4.w = f2bf(acc[mi][ni][g * 4 + 3]);
                    *(ushort4*)(Vt + ((size_t)(bb * 16 + h) * 64 + d) * 1024 + nn) = o4;
                }
            }
        return;
    }

    #pragma unroll
    for (int mi = 0; mi < 2; mi++)
        #pragma unroll
        for (int ni = 0; ni < 2; ni++) {
            int col = colw + ni * 32 + n_l;
            float bv = (flags & FLAG_BIAS) ? bias[col] : 0.0f;
            #pragma unroll
            for (int reg = 0; reg < 16; reg++) {
                int row = row0 + wm * 64 + mi * 32 + (reg & 3) + 8 * (reg >> 2) + 4 * hi;
                float v = acc[mi][ni][reg] + bv;
                if (flags & FLAG_GELU) v = gelu_fast(v);
                Cb[(size_t)row * ldcb + col] = f2bf(v);
            }
        }
}

// ---------------- fused split-K reduce (bf16 partials) + residual + optional LN ----------------
__global__ __launch_bounds__(256) void reduce_ln_kernel(const unsigned short* __restrict__ P,
                                                        int nsplit,
                                                        const float* __restrict__ bias,
                                                        const float* __restrict__ resid,
                                                        float* __restrict__ xc_out,
                                                        unsigned short* __restrict__ xn_out,
                                                        const float* __restrict__ g,
                                                        const float* __restrict__ b) {
    const int MN = NTOK * DIM_;
    int row = blockIdx.x;
    int t = threadIdx.x;
    size_t i = (size_t)row * DIM_ + t * 4;
    float4 y  = *(const float4*)(resid + i);
    float4 bi = *(const float4*)(bias + t * 4);
    y.x += bi.x; y.y += bi.y; y.z += bi.z; y.w += bi.w;
    for (int z = 0; z < nsplit; z++) {
        ushort4 p = *(const ushort4*)(P + (size_t)z * MN + i);
        y.x += bf2f(p.x); y.y += bf2f(p.y); y.z += bf2f(p.z); y.w += bf2f(p.w);
    }
    *(float4*)(xc_out + i) = y;
    if (!xn_out) return;

    float s  = y.x + y.y + y.z + y.w;
    float sq = y.x*y.x + y.y*y.y + y.z*y.z + y.w*y.w;
    __shared__ float ssum[256], ssq[256];
    ssum[t] = s; ssq[t] = sq;
    __syncthreads();
    for (int o = 128; o > 0; o >>= 1) {
        if (t < o) { ssum[t] += ssum[t+o]; ssq[t] += ssq[t+o]; }
        __syncthreads();
    }
    float mu  = ssum[0] * (1.0f / DIM_);
    float var = ssq[0] * (1.0f / DIM_) - mu * mu;
    float r = rsqrtf(var + EPS_);
    float4 gg = *(const float4*)(g + t * 4);
    float4 bb = *(const float4*)(b + t * 4);
    ushort4 o4;
    o4.x = f2bf((y.x - mu) * r * gg.x + bb.x);
    o4.y = f2bf((y.y - mu) * r * gg.y + bb.y);
    o4.z = f2bf((y.z - mu) * r * gg.z + bb.z);
    o4.w = f2bf((y.w - mu) * r * gg.w + bb.w);
    ((ushort4*)(xn_out + (size_t)row * DIM_))[t] = o4;
}

// ---------------- MFMA flash attention v3 + T5 setprio ----------------
//  - T14 async-STAGE: K/V double-buffered in LDS; tile t+1's global loads are
//    issued into registers right after the barrier and written at the top of
//    t+1, so HBM/L2 latency hides under QK+softmax+PV compute.
//  - single barrier per j-tile; Ps is wave-private.
//  - T1 XCD grouping: qt on HIGH index bits -> 8 q-blocks sharing one (b,h)'s
//    K/V are congruent mod 8 -> same XCD L2.
//  - T5 (new): s_setprio(1) around the QK and PV MFMA clusters. Waves here
//    drift between softmax VALU work and MFMA between barriers (phase
//    diversity), the regime where setprio pays (m191 attn +4-7%; null only on
//    lockstep GEMM waves, m190).
__global__ __launch_bounds__(512) void fattn_kernel(const unsigned short* __restrict__ qk,
                                                    const unsigned short* __restrict__ VtG,
                                                    unsigned short* __restrict__ out) {
    int idx = blockIdx.x;
    int qt = idx >> 5;           // 0..7
    int h  = idx & 15;
    int b  = (idx >> 4) & 1;
    int t  = threadIdx.x;
    int lane = t & 63, w = t >> 6;
    int m = lane & 15, quad = lane >> 4;

    __shared__ unsigned short Ks[2][64 * 64];    // [j][d], swizzled, double-buffered
    __shared__ unsigned short Vs[2][64 * 64];    // [d][j], swizzled, double-buffered
    __shared__ unsigned short Ps[8][16 * 72];    // per-wave P [i][j], padded

    const size_t base = (size_t)b * NSEQ * 2048;
    const int i0 = qt * 128 + w * 16;

    bf16x8 aq0, aq1;
    {
        const unsigned short* qrow = qk + base + (size_t)(i0 + m) * 2048 + h * HD;
        aq0 = *(const bf16x8*)(qrow + quad * 8);
        aq1 = *(const bf16x8*)(qrow + 32 + quad * 8);
    }

    f32x4 Oacc[4];
    #pragma unroll
    for (int dt = 0; dt < 4; dt++) Oacc[dt] = (f32x4){0.f, 0.f, 0.f, 0.f};
    float lsum[4] = {0.f, 0.f, 0.f, 0.f};

    int srow = t >> 3;                 // 0..63
    int schunk = t & 7;
    int swc = schunk ^ (srow & 7);
    const unsigned short* Kg = qk + base + 1024 + h * HD + (size_t)srow * 2048 + schunk * 8;
    const unsigned short* Vg = VtG + ((size_t)(b * 16 + h) * 64 + srow) * 1024 + schunk * 8;
    const int sloff = srow * 64 + swc * 8;

    // prefetch tile 0 into registers
    bf16x8 kreg = *(const bf16x8*)(Kg);
    bf16x8 vreg = *(const bf16x8*)(Vg);

    for (int jt = 0; jt < NSEQ / 64; jt++) {
        int cur = jt & 1;
        *(bf16x8*)&Ks[cur][sloff] = kreg;
        *(bf16x8*)&Vs[cur][sloff] = vreg;
        __syncthreads();
        if (jt + 1 < NSEQ / 64) {       // issue next tile now; lands during compute
            kreg = *(const bf16x8*)(Kg + (size_t)(jt + 1) * 64 * 2048);
            vreg = *(const bf16x8*)(Vg + (jt + 1) * 64);
        }

        f32x4 s[4];
        __builtin_amdgcn_s_setprio(1);
        #pragma unroll
        for (int nt = 0; nt < 4; nt++) {
            int jr = nt * 16 + m;
            const unsigned short* kr = &Ks[cur][jr * 64];
            int x7 = jr & 7;
            bf16x8 b0 = *(const bf16x8*)(kr + (quad ^ x7) * 8);
            bf16x8 b1 = *(const bf16x8*)(kr + ((quad + 4) ^ x7) * 8);
            f32x4 a = (f32x4){0.f, 0.f, 0.f, 0.f};
            a = __builtin_amdgcn_mfma_f32_16x16x32_bf16(aq0, b0, a, 0, 0, 0);
            a = __builtin_amdgcn_mfma_f32_16x16x32_bf16(aq1, b1, a, 0, 0, 0);
            s[nt] = a;
        }
        __builtin_amdgcn_s_setprio(0);

        #pragma unroll
        for (int r = 0; r < 4; r++) {
            float p0 = __expf(s[0][r]);
            float p1 = __expf(s[1][r]);
            float p2 = __expf(s[2][r]);
            float p3 = __expf(s[3][r]);
            lsum[r] += p0 + p1 + p2 + p3;
            unsigned short* pr = &Ps[w][(quad * 4 + r) * 72 + m];
            pr[0]  = f2bf(p0);
            pr[16] = f2bf(p1);
            pr[32] = f2bf(p2);
            pr[48] = f2bf(p3);
        }

        const unsigned short* pa = &Ps[w][m * 72 + quad * 8];
        bf16x8 ap0 = *(const bf16x8*)pa;
        bf16x8 ap1 = *(const bf16x8*)(pa + 32);
        __builtin_amdgcn_s_setprio(1);
        #pragma unroll
        for (int dt = 0; dt < 4; dt++) {
            int dr = dt * 16 + m;
            const unsigned short* vr = &Vs[cur][dr * 64];
            int x7 = dr & 7;
            bf16x8 b0 = *(const bf16x8*)(vr + (quad ^ x7) * 8);
            bf16x8 b1 = *(const bf16x8*)(vr + ((quad + 4) ^ x7) * 8);
            Oacc[dt] = __builtin_amdgcn_mfma_f32_16x16x32_bf16(ap0, b0, Oacc[dt], 0, 0, 0);
            Oacc[dt] = __builtin_amdgcn_mfma_f32_16x16x32_bf16(ap1, b1, Oacc[dt], 0, 0, 0);
        }
        __builtin_amdgcn_s_setprio(0);
        // no trailing barrier: next iter writes the other LDS buffer
    }

    #pragma unroll
    for (int r = 0; r < 4; r++) {
        float rs = lsum[r];
        rs += __shfl_xor(rs, 1);
        rs += __shfl_xor(rs, 2);
        rs += __shfl_xor(rs, 4);
        rs += __shfl_xor(rs, 8);
        lsum[r] = rs;
    }

    #pragma unroll
    for (int r = 0; r < 4; r++) {
        float inv = 1.0f / lsum[r];
        int row = i0 + quad * 4 + r;
        unsigned short* orow = out + ((size_t)(b * NSEQ + row)) * DIM_ + h * HD + m;
        orow[0]  = f2bf(Oacc[0][r] * inv);
        orow[16] = f2bf(Oacc[1][r] * inv);
        orow[32] = f2bf(Oacc[2][r] * inv);
        orow[48] = f2bf(Oacc[3][r] * inv);
    }
}

extern "C" void kernel_launch(void* const* d_in, const int* in_sizes, int n_in,
                              void* d_out, int out_size, void* d_ws, size_t ws_size,
                              hipStream_t stream) {
    const float* x    = (const float*)d_in[0];
    const float* ln1g = (const float*)d_in[1];
    const float* ln1b = (const float*)d_in[2];
    const float* wqkv = (const float*)d_in[3];
    const float* wo   = (const float*)d_in[4];
    const float* bo   = (const float*)d_in[5];
    const float* ln2g = (const float*)d_in[6];
    const float* ln2b = (const float*)d_in[7];
    const float* w1   = (const float*)d_in[8];
    const float* b1   = (const float*)d_in[9];
    const float* w2   = (const float*)d_in[10];
    const float* b2   = (const float*)d_in[11];
    float* out = (float*)d_out;

    // layout (MB): xcur 0-8 | aout 8-12 | xn 12-16 | qk 16-24 | VtG 24-28 |
    //              hdn 28-44 | wtqkv 44-50 | wto 50-52 | wt1 52-60 | wt2 60-68
    // overlays (bf16 split-K partials, 4 x 4MB = 16MB):
    //   o-partials    @12-28 (xn+qk+VtG dead during o-gemm)
    //   mlp2-partials @ 8-24 (aout+xn+qk dead during mlp2-gemm)
    char* ws = (char*)d_ws;
    float*          xcur = (float*)(ws);
    unsigned short* aout = (unsigned short*)(ws + (8u<<20));
    unsigned short* xn   = (unsigned short*)(ws + (12u<<20));
    unsigned short* qk   = (unsigned short*)(ws + (16u<<20));
    unsigned short* VtG  = (unsigned short*)(ws + (24u<<20));
    unsigned short* hdn  = (unsigned short*)(ws + (28u<<20));
    unsigned short* wtqkv= (unsigned short*)(ws + (44u<<20));
    unsigned short* wto  = (unsigned short*)(ws + (50u<<20));
    unsigned short* wt1  = (unsigned short*)(ws + (52u<<20));
    unsigned short* wt2  = (unsigned short*)(ws + (60u<<20));
    unsigned short* opart  = (unsigned short*)(ws + (12u<<20));
    unsigned short* m2part = (unsigned short*)(ws + (8u<<20));

    wconv_kernel<<<dim3(3*DIM_/32, DIM_/32), dim3(32,8), 0, stream>>>(wqkv, wtqkv, DIM_, 3*DIM_,
                                                                      0.03125f, DIM_);
    wconv_kernel<<<dim3(DIM_/32,   DIM_/32), dim3(32,8), 0, stream>>>(wo,   wto, DIM_, DIM_, 1.f, 0);
    wconv_kernel<<<dim3(MLP_/32,   DIM_/32), dim3(32,8), 0, stream>>>(w1,   wt1, DIM_, MLP_, 1.f, 0);
    wconv_kernel<<<dim3(DIM_/32,   MLP_/32), dim3(32,8), 0, stream>>>(w2,   wt2, MLP_, DIM_, 1.f, 0);

    for (int layer = 0; layer < 4; layer++) {
        if (layer == 0)
            ln_kernel<<<NTOK, 256, 0, stream>>>(x, xn, ln1g, ln1b);
        // qkv: 384 blocks (nx=24, gy=16, gz=1), NT=16; Q,K -> qk; V -> VtG
        gemm128_kernel<16><<<384, 256, 0, stream>>>(
            xn, wtqkv, qk, VtG, nullptr, nullptr,
            NTOK, 3*DIM_, DIM_, 2048, 24, 1, FLAG_QKV);
        fattn_kernel<<<256, 512, 0, stream>>>(qk, VtG, aout);
        // o-proj: SK=4 (nx=8, gy=16, gz=4), NT=4 (KC=256) -> bf16 partials
        gemm128_kernel<4><<<512, 256, 0, stream>>>(
            aout, wto, nullptr, nullptr, opart, nullptr,
            NTOK, DIM_, DIM_, 0, 8, 4, FLAG_PART);
        reduce_ln_kernel<<<NTOK, 256, 0, stream>>>(
            opart, 4, bo, (layer == 0 ? x : xcur), xcur, xn, ln2g, ln2b);
        // mlp1: 512 blocks (nx=32, gy=16, gz=1), NT=16; bias+gelu, bf16 out
        gemm128_kernel<16><<<512, 256, 0, stream>>>(
            xn, wt1, hdn, nullptr, nullptr, b1,
            NTOK, MLP_, DIM_, MLP_, 32, 1, FLAG_BIAS | FLAG_GELU);
        // mlp2: SK=4 (nx=8, gy=16, gz=4), NT=16 (KC=1024) -> bf16 partials
        gemm128_kernel<16><<<512, 256, 0, stream>>>(
            hdn, wt2, nullptr, nullptr, m2part, nullptr,
            NTOK, DIM_, MLP_, 0, 8, 4, FLAG_PART);
        if (layer < 3)
            reduce_ln_kernel<<<NTOK, 256, 0, stream>>>(
                m2part, 4, b2, xcur, xcur, xn, ln1g, ln1b);
        else
            reduce_ln_kernel<<<NTOK, 256, 0, stream>>>(
                m2part, 4, b2, xcur, out, nullptr, nullptr, nullptr);
    }
}